// Round 3
// baseline (557.472 us; speedup 1.0000x reference)
//
#include <hip/hip_runtime.h>
#include <math.h>

#define BATCH 8
#define KQ 256
#define DIM 50257
#define KNN 8
#define N_CLASS 4
#define INV_T 20.0f       // 1/0.05
#define LLSTRIDE 50264    // DIM+4 rounded up to multiple of 8 (keeps rows 16B-alignable)

// ---------------- kernel 1: 4 phase-shifted log(logits) copies ----------------
// Copy c stores element d of row b at ll4[(c*B+b)*LLSTRIDE + c + d], so a reader
// that peels (4-c)&3 elements lands on a 16B boundary for BOTH qa and ll.
__global__ __launch_bounds__(256) void log_logits_kernel(
        const float* __restrict__ logits, float* __restrict__ ll4, int n) {
    int i = blockIdx.x * 256 + threadIdx.x;     // i = b*DIM + d
    if (i >= n) return;
    int b = i / DIM;
    int d = i - b * DIM;
    float v = __logf(logits[i]);
    #pragma unroll
    for (int c = 0; c < 4; ++c)
        ll4[((size_t)(c * BATCH + b)) * LLSTRIDE + c + d] = v;
}

// ---------------- kernel 2: per-(b,k) KL distance reduction ----------------
// grid = B*K blocks, 256 threads. Both the 412MB qa stream and the L2-resident
// ll copy are aligned float4 streams: 2 VMEM instructions per 4 elements.
__global__ __launch_bounds__(256) void dists_kernel(
        const float* __restrict__ qa, const float* __restrict__ ll4,
        float* __restrict__ dists) {
    const int bk = blockIdx.x;          // b*256 + k
    const int b  = bk >> 8;
    const int c  = bk & 3;              // phase -> which shifted ll copy
    const float* __restrict__ qrow = qa  + (size_t)bk * DIM;
    const float* __restrict__ lrow = ll4 + ((size_t)(c * BATCH + b)) * LLSTRIDE + c; // lrow[d] = log(logits[b][d])

    const int peel = (4 - c) & 3;                // scalars to peel for 16B alignment
    const int nv   = (DIM - peel) >> 2;          // aligned float4 count
    const int tail = peel + nv * 4;              // first tail scalar index
    const int t = threadIdx.x;

    float ax = 0.f, ay = 0.f, az = 0.f, aw = 0.f;
    const float4* __restrict__ q4 = (const float4*)(qrow + peel);
    const float4* __restrict__ l4 = (const float4*)(lrow + peel);
    for (int i = t; i < nv; i += 256) {
        float4 q = q4[i];
        float4 l = l4[i];
        ax += q.x * (__logf(q.x) - l.x);
        ay += q.y * (__logf(q.y) - l.y);
        az += q.z * (__logf(q.z) - l.z);
        aw += q.w * (__logf(q.w) - l.w);
    }
    float s = (ax + ay) + (az + aw);

    // peel scalars (indices [0, peel)) and tail scalars (indices [tail, DIM))
    if (t < peel) {
        float q = qrow[t];
        s += q * (__logf(q) - lrow[t]);
    }
    int tn = DIM - tail;                          // 0..3
    if (t >= 4 && t < 4 + tn) {
        int d = tail + (t - 4);
        float q = qrow[d];
        s += q * (__logf(q) - lrow[d]);
    }

    // wave reduce (64 lanes) then cross-wave via LDS
    for (int o = 32; o > 0; o >>= 1) s += __shfl_xor(s, o, 64);
    __shared__ float part[4];
    if ((t & 63) == 0) part[t >> 6] = s;
    __syncthreads();
    if (t == 0) {
        float tot = (part[0] + part[1]) + (part[2] + part[3]);
        dists[bk] = tot * (1.0f / (float)DIM);
    }
}

// ---------------- kernel 3: top-8 + softmax + class scatter ----------------
// one wave per batch row; iterative argmax, tie -> lower index (lax.top_k).
__global__ __launch_bounds__(64) void topk_kernel(
        const float* __restrict__ dists, const int* __restrict__ labels,
        float* __restrict__ out) {
    const int b = blockIdx.x;
    const int lane = threadIdx.x;
    const int base = lane * 4;
    const float* __restrict__ drow = dists + b * KQ;

    float v[4];
    #pragma unroll
    for (int j = 0; j < 4; ++j) v[j] = -INV_T * drow[base + j];

    float topv[KNN]; int topi[KNN];
    #pragma unroll
    for (int it = 0; it < KNN; ++it) {
        float lv = v[0]; int li = base;
        #pragma unroll
        for (int j = 1; j < 4; ++j)
            if (v[j] > lv || (v[j] == lv && base + j < li)) { lv = v[j]; li = base + j; }
        // full-wave argmax via xor butterfly; all lanes converge
        #pragma unroll
        for (int o = 32; o > 0; o >>= 1) {
            float ov = __shfl_xor(lv, o, 64);
            int   oi = __shfl_xor(li, o, 64);
            if (ov > lv || (ov == lv && oi < li)) { lv = ov; li = oi; }
        }
        topv[it] = lv; topi[it] = li;
        if (li >= base && li < base + 4) v[li - base] = -INFINITY;
    }

    if (lane == 0) {
        float m = topv[0];                 // max (sorted descending)
        float w[KNN], sum = 0.f;
        #pragma unroll
        for (int i = 0; i < KNN; ++i) { w[i] = __expf(topv[i] - m); sum += w[i]; }
        float p[N_CLASS] = {0.f, 0.f, 0.f, 0.f};
        #pragma unroll
        for (int i = 0; i < KNN; ++i) p[labels[b * KQ + topi[i]]] += w[i];
        float inv = 1.0f / sum;
        #pragma unroll
        for (int c = 0; c < N_CLASS; ++c) out[b * N_CLASS + c] = p[c] * inv;
    }
}

extern "C" void kernel_launch(void* const* d_in, const int* in_sizes, int n_in,
                              void* d_out, int out_size, void* d_ws, size_t ws_size,
                              hipStream_t stream) {
    const float* logits = (const float*)d_in[0];   // [B, DIM]
    const float* qa     = (const float*)d_in[1];   // [B, K, DIM]
    const int*   labels = (const int*)d_in[2];     // [B, K]
    float* out = (float*)d_out;                    // [B, N_CLASS]

    // ws layout: ll4 [4*B*LLSTRIDE] f32 (phase-shifted log copies), then dists [B*K] f32
    float* ll4   = (float*)d_ws;
    float* dists = ll4 + (size_t)4 * BATCH * LLSTRIDE;

    const int n_ll = BATCH * DIM;
    log_logits_kernel<<<(n_ll + 255) / 256, 256, 0, stream>>>(logits, ll4, n_ll);
    dists_kernel<<<BATCH * KQ, 256, 0, stream>>>(qa, ll4, dists);
    topk_kernel<<<BATCH, 64, 0, stream>>>(dists, labels, out);
}

// Round 6
// 545.546 us; speedup vs baseline: 1.0219x; 1.0219x over previous
//
#include <hip/hip_runtime.h>
#include <math.h>

#define BATCH 8
#define KQ 256
#define DIM 50257
#define KNN 8
#define N_CLASS 4
#define INV_T 20.0f       // 1/0.05
#define LLSTRIDE 50264    // DIM+4 rounded up to multiple of 8 (keeps rows 16B-alignable)

// ---------------- kernel 1: 4 phase-shifted log(logits) copies ----------------
__global__ __launch_bounds__(256) void log_logits_kernel(
        const float* __restrict__ logits, float* __restrict__ ll4, int n) {
    int i = blockIdx.x * 256 + threadIdx.x;     // i = b*DIM + d
    if (i >= n) return;
    int b = i / DIM;
    int d = i - b * DIM;
    float v = __logf(logits[i]);
    #pragma unroll
    for (int c = 0; c < 4; ++c)
        ll4[((size_t)(c * BATCH + b)) * LLSTRIDE + c + d] = v;
}

// ---------------- kernel 2: per-(b,k) KL distance reduction ----------------
// grid = B*K blocks, 256 threads. 4x-batched loads: 8 dwordx4 in flight per
// wave before any waitcnt-consume -> 4x memory-level parallelism vs R1/R3
// (which were latency-bound at ~2.5 TB/s with <=2 loads outstanding).
__global__ __launch_bounds__(256) void dists_kernel(
        const float* __restrict__ qa, const float* __restrict__ ll4,
        float* __restrict__ dists) {
    const int bk = blockIdx.x;          // b*256 + k
    const int b  = bk >> 8;
    const int c  = bk & 3;              // phase -> which shifted ll copy
    const float* __restrict__ qrow = qa  + (size_t)bk * DIM;
    const float* __restrict__ lrow = ll4 + ((size_t)(c * BATCH + b)) * LLSTRIDE + c;

    const int peel = (4 - c) & 3;                // scalars to peel for 16B alignment
    const int nv   = (DIM - peel) >> 2;          // aligned float4 count
    const int tail = peel + nv * 4;              // first tail scalar index
    const int t = threadIdx.x;

    float ax = 0.f, ay = 0.f, az = 0.f, aw = 0.f;
    const float4* __restrict__ q4 = (const float4*)(qrow + peel);
    const float4* __restrict__ l4 = (const float4*)(lrow + peel);

    int i = t;
    // main batched loop: 4 q4 + 4 l4 loads issued before any use
    for (; i + 768 < nv; i += 1024) {
        float4 q0 = q4[i];
        float4 q1 = q4[i + 256];
        float4 q2 = q4[i + 512];
        float4 q3 = q4[i + 768];
        float4 l0 = l4[i];
        float4 l1 = l4[i + 256];
        float4 l2 = l4[i + 512];
        float4 l3 = l4[i + 768];
        // same per-accumulator sequence as the unbatched loop (i ascending)
        ax += q0.x * (__logf(q0.x) - l0.x);
        ay += q0.y * (__logf(q0.y) - l0.y);
        az += q0.z * (__logf(q0.z) - l0.z);
        aw += q0.w * (__logf(q0.w) - l0.w);
        ax += q1.x * (__logf(q1.x) - l1.x);
        ay += q1.y * (__logf(q1.y) - l1.y);
        az += q1.z * (__logf(q1.z) - l1.z);
        aw += q1.w * (__logf(q1.w) - l1.w);
        ax += q2.x * (__logf(q2.x) - l2.x);
        ay += q2.y * (__logf(q2.y) - l2.y);
        az += q2.z * (__logf(q2.z) - l2.z);
        aw += q2.w * (__logf(q2.w) - l2.w);
        ax += q3.x * (__logf(q3.x) - l3.x);
        ay += q3.y * (__logf(q3.y) - l3.y);
        az += q3.z * (__logf(q3.z) - l3.z);
        aw += q3.w * (__logf(q3.w) - l3.w);
    }
    // tail iterations (<=3)
    for (; i < nv; i += 256) {
        float4 q = q4[i];
        float4 l = l4[i];
        ax += q.x * (__logf(q.x) - l.x);
        ay += q.y * (__logf(q.y) - l.y);
        az += q.z * (__logf(q.z) - l.z);
        aw += q.w * (__logf(q.w) - l.w);
    }
    float s = (ax + ay) + (az + aw);

    // peel scalars (indices [0, peel)) and tail scalars (indices [tail, DIM))
    if (t < peel) {
        float q = qrow[t];
        s += q * (__logf(q) - lrow[t]);
    }
    int tn = DIM - tail;                          // 0..3
    if (t >= 4 && t < 4 + tn) {
        int d = tail + (t - 4);
        float q = qrow[d];
        s += q * (__logf(q) - lrow[d]);
    }

    // wave reduce (64 lanes) then cross-wave via LDS
    for (int o = 32; o > 0; o >>= 1) s += __shfl_xor(s, o, 64);
    __shared__ float part[4];
    if ((t & 63) == 0) part[t >> 6] = s;
    __syncthreads();
    if (t == 0) {
        float tot = (part[0] + part[1]) + (part[2] + part[3]);
        dists[bk] = tot * (1.0f / (float)DIM);
    }
}

// ---------------- kernel 3: top-8 + softmax + class scatter ----------------
__global__ __launch_bounds__(64) void topk_kernel(
        const float* __restrict__ dists, const int* __restrict__ labels,
        float* __restrict__ out) {
    const int b = blockIdx.x;
    const int lane = threadIdx.x;
    const int base = lane * 4;
    const float* __restrict__ drow = dists + b * KQ;

    float v[4];
    #pragma unroll
    for (int j = 0; j < 4; ++j) v[j] = -INV_T * drow[base + j];

    float topv[KNN]; int topi[KNN];
    #pragma unroll
    for (int it = 0; it < KNN; ++it) {
        float lv = v[0]; int li = base;
        #pragma unroll
        for (int j = 1; j < 4; ++j)
            if (v[j] > lv || (v[j] == lv && base + j < li)) { lv = v[j]; li = base + j; }
        #pragma unroll
        for (int o = 32; o > 0; o >>= 1) {
            float ov = __shfl_xor(lv, o, 64);
            int   oi = __shfl_xor(li, o, 64);
            if (ov > lv || (ov == lv && oi < li)) { lv = ov; li = oi; }
        }
        topv[it] = lv; topi[it] = li;
        if (li >= base && li < base + 4) v[li - base] = -INFINITY;
    }

    if (lane == 0) {
        float m = topv[0];                 // max (sorted descending)
        float w[KNN], sum = 0.f;
        #pragma unroll
        for (int i = 0; i < KNN; ++i) { w[i] = __expf(topv[i] - m); sum += w[i]; }
        float p[N_CLASS] = {0.f, 0.f, 0.f, 0.f};
        #pragma unroll
        for (int i = 0; i < KNN; ++i) p[labels[b * KQ + topi[i]]] += w[i];
        float inv = 1.0f / sum;
        #pragma unroll
        for (int c = 0; c < N_CLASS; ++c) out[b * N_CLASS + c] = p[c] * inv;
    }
}

extern "C" void kernel_launch(void* const* d_in, const int* in_sizes, int n_in,
                              void* d_out, int out_size, void* d_ws, size_t ws_size,
                              hipStream_t stream) {
    const float* logits = (const float*)d_in[0];   // [B, DIM]
    const float* qa     = (const float*)d_in[1];   // [B, K, DIM]
    const int*   labels = (const int*)d_in[2];     // [B, K]
    float* out = (float*)d_out;                    // [B, N_CLASS]

    float* ll4   = (float*)d_ws;
    float* dists = ll4 + (size_t)4 * BATCH * LLSTRIDE;

    const int n_ll = BATCH * DIM;
    log_logits_kernel<<<(n_ll + 255) / 256, 256, 0, stream>>>(logits, ll4, n_ll);
    dists_kernel<<<BATCH * KQ, 256, 0, stream>>>(qa, ll4, dists);
    topk_kernel<<<BATCH, 64, 0, stream>>>(dists, labels, out);
}

// Round 7
// 535.671 us; speedup vs baseline: 1.0407x; 1.0184x over previous
//
#include <hip/hip_runtime.h>
#include <math.h>

#define BATCH 8
#define KQ 256
#define DIM 50257
#define KNN 8
#define N_CLASS 4
#define INV_T 20.0f       // 1/0.05
#define LL2STRIDE 50260   // DIM+2 rounded up to multiple of 4

typedef float vf4 __attribute__((ext_vector_type(4)));

__device__ __forceinline__ vf4 nt_load4(const float* p) {
    return __builtin_nontemporal_load((const vf4*)p);
}

// ---------------- kernel 1: 2 shift-copies of log(logits) ----------------
// Copy s (s=0,1) stores element d of row b at ll2[(s*B+b)*LL2STRIDE + s + d].
// Reader with phase c=k&3 peels peel=(4-c)&3 scalars and picks s=k&1; then
// (row_base + s + peel) is even -> aligned float2 loads. Table = 3.2 MB,
// fits per-XCD 4 MiB L2 and stays resident because qa uses NT loads.
__global__ __launch_bounds__(256) void log_logits_kernel(
        const float* __restrict__ logits, float* __restrict__ ll2, int n) {
    int i = blockIdx.x * 256 + threadIdx.x;     // i = b*DIM + d
    if (i >= n) return;
    int b = i / DIM;
    int d = i - b * DIM;
    float v = __logf(logits[i]);
    #pragma unroll
    for (int s = 0; s < 2; ++s)
        ll2[((size_t)(s * BATCH + b)) * LL2STRIDE + s + d] = v;
}

// ---------------- kernel 2: per-(b,k) KL distance reduction ----------------
// grid = B*K blocks, 256 threads. qa: NT float4 loads (no L2 allocation ->
// no thrash). ll: L2-resident table, aligned float2 loads. 4x-batched for MLP.
__global__ __launch_bounds__(256) void dists_kernel(
        const float* __restrict__ qa, const float* __restrict__ ll2,
        float* __restrict__ dists) {
    const int bk = blockIdx.x;          // b*256 + k
    const int b  = bk >> 8;
    const int c  = bk & 3;              // row phase mod 4
    const int s  = bk & 1;              // shift-copy select (= peel&1)
    const float* __restrict__ qrow  = qa  + (size_t)bk * DIM;
    const float* __restrict__ lrow2 = ll2 + ((size_t)(s * BATCH + b)) * LL2STRIDE + s; // lrow2[d] = log(logits[b][d])

    const int peel = (4 - c) & 3;                // qrow+peel is 16B-aligned; lrow2+peel is 8B-aligned
    const int nv   = (DIM - peel) >> 2;          // aligned float4 count
    const int tail = peel + nv * 4;              // first tail scalar index
    const int t = threadIdx.x;

    float ax = 0.f, ay = 0.f, az = 0.f, aw = 0.f;
    const float*  __restrict__ qbase = qrow + peel;
    const float2* __restrict__ l2 = (const float2*)(lrow2 + peel);

    int i = t;
    // main batched loop: 4 NT q4 + 8 l2 loads issued before any use
    for (; i + 768 < nv; i += 1024) {
        vf4 q0 = nt_load4(qbase + 4 * i);
        vf4 q1 = nt_load4(qbase + 4 * (i + 256));
        vf4 q2 = nt_load4(qbase + 4 * (i + 512));
        vf4 q3 = nt_load4(qbase + 4 * (i + 768));
        float2 l0a = l2[2 * i],             l0b = l2[2 * i + 1];
        float2 l1a = l2[2 * (i + 256)],     l1b = l2[2 * (i + 256) + 1];
        float2 l2a = l2[2 * (i + 512)],     l2b = l2[2 * (i + 512) + 1];
        float2 l3a = l2[2 * (i + 768)],     l3b = l2[2 * (i + 768) + 1];
        // same per-accumulator sequence as before (i ascending)
        ax += q0.x * (__logf(q0.x) - l0a.x);
        ay += q0.y * (__logf(q0.y) - l0a.y);
        az += q0.z * (__logf(q0.z) - l0b.x);
        aw += q0.w * (__logf(q0.w) - l0b.y);
        ax += q1.x * (__logf(q1.x) - l1a.x);
        ay += q1.y * (__logf(q1.y) - l1a.y);
        az += q1.z * (__logf(q1.z) - l1b.x);
        aw += q1.w * (__logf(q1.w) - l1b.y);
        ax += q2.x * (__logf(q2.x) - l2a.x);
        ay += q2.y * (__logf(q2.y) - l2a.y);
        az += q2.z * (__logf(q2.z) - l2b.x);
        aw += q2.w * (__logf(q2.w) - l2b.y);
        ax += q3.x * (__logf(q3.x) - l3a.x);
        ay += q3.y * (__logf(q3.y) - l3a.y);
        az += q3.z * (__logf(q3.z) - l3b.x);
        aw += q3.w * (__logf(q3.w) - l3b.y);
    }
    // tail iterations (<=3)
    for (; i < nv; i += 256) {
        vf4 q = nt_load4(qbase + 4 * i);
        float2 la = l2[2 * i], lb = l2[2 * i + 1];
        ax += q.x * (__logf(q.x) - la.x);
        ay += q.y * (__logf(q.y) - la.y);
        az += q.z * (__logf(q.z) - lb.x);
        aw += q.w * (__logf(q.w) - lb.y);
    }
    float sacc = (ax + ay) + (az + aw);

    // peel scalars (indices [0, peel)) and tail scalars (indices [tail, DIM))
    if (t < peel) {
        float q = qrow[t];
        sacc += q * (__logf(q) - lrow2[t]);
    }
    int tn = DIM - tail;                          // 0..3
    if (t >= 4 && t < 4 + tn) {
        int d = tail + (t - 4);
        float q = qrow[d];
        sacc += q * (__logf(q) - lrow2[d]);
    }

    // wave reduce (64 lanes) then cross-wave via LDS
    for (int o = 32; o > 0; o >>= 1) sacc += __shfl_xor(sacc, o, 64);
    __shared__ float part[4];
    if ((t & 63) == 0) part[t >> 6] = sacc;
    __syncthreads();
    if (t == 0) {
        float tot = (part[0] + part[1]) + (part[2] + part[3]);
        dists[bk] = tot * (1.0f / (float)DIM);
    }
}

// ---------------- kernel 3: top-8 + softmax + class scatter ----------------
__global__ __launch_bounds__(64) void topk_kernel(
        const float* __restrict__ dists, const int* __restrict__ labels,
        float* __restrict__ out) {
    const int b = blockIdx.x;
    const int lane = threadIdx.x;
    const int base = lane * 4;
    const float* __restrict__ drow = dists + b * KQ;

    float v[4];
    #pragma unroll
    for (int j = 0; j < 4; ++j) v[j] = -INV_T * drow[base + j];

    float topv[KNN]; int topi[KNN];
    #pragma unroll
    for (int it = 0; it < KNN; ++it) {
        float lv = v[0]; int li = base;
        #pragma unroll
        for (int j = 1; j < 4; ++j)
            if (v[j] > lv || (v[j] == lv && base + j < li)) { lv = v[j]; li = base + j; }
        #pragma unroll
        for (int o = 32; o > 0; o >>= 1) {
            float ov = __shfl_xor(lv, o, 64);
            int   oi = __shfl_xor(li, o, 64);
            if (ov > lv || (ov == lv && oi < li)) { lv = ov; li = oi; }
        }
        topv[it] = lv; topi[it] = li;
        if (li >= base && li < base + 4) v[li - base] = -INFINITY;
    }

    if (lane == 0) {
        float m = topv[0];                 // max (sorted descending)
        float w[KNN], sum = 0.f;
        #pragma unroll
        for (int i = 0; i < KNN; ++i) { w[i] = __expf(topv[i] - m); sum += w[i]; }
        float p[N_CLASS] = {0.f, 0.f, 0.f, 0.f};
        #pragma unroll
        for (int i = 0; i < KNN; ++i) p[labels[b * KQ + topi[i]]] += w[i];
        float inv = 1.0f / sum;
        #pragma unroll
        for (int c = 0; c < N_CLASS; ++c) out[b * N_CLASS + c] = p[c] * inv;
    }
}

extern "C" void kernel_launch(void* const* d_in, const int* in_sizes, int n_in,
                              void* d_out, int out_size, void* d_ws, size_t ws_size,
                              hipStream_t stream) {
    const float* logits = (const float*)d_in[0];   // [B, DIM]
    const float* qa     = (const float*)d_in[1];   // [B, K, DIM]
    const int*   labels = (const int*)d_in[2];     // [B, K]
    float* out = (float*)d_out;                    // [B, N_CLASS]

    // ws layout: ll2 [2*B*LL2STRIDE] f32 (shift-copies), then dists [B*K] f32
    float* ll2   = (float*)d_ws;
    float* dists = ll2 + (size_t)2 * BATCH * LL2STRIDE;

    const int n_ll = BATCH * DIM;
    log_logits_kernel<<<(n_ll + 255) / 256, 256, 0, stream>>>(logits, ll2, n_ll);
    dists_kernel<<<BATCH * KQ, 256, 0, stream>>>(qa, ll2, dists);
    topk_kernel<<<BATCH, 64, 0, stream>>>(dists, labels, out);
}